// Round 18
// baseline (157.085 us; speedup 1.0000x reference)
//
#include <hip/hip_runtime.h>
#include <cstdint>
#include <cstddef>

typedef unsigned short u16;
typedef __attribute__((ext_vector_type(4))) float f32x4;
typedef __attribute__((ext_vector_type(8))) short bf16x8;

#define LN_EPS 1e-5f
#define WAITV(n) asm volatile("s_waitcnt vmcnt(" #n ")" ::: "memory")
#define LGKM0    asm volatile("s_waitcnt lgkmcnt(0)" ::: "memory")
#define BAR()    do { __builtin_amdgcn_s_barrier(); asm volatile("" ::: "memory"); } while (0)

__device__ __forceinline__ u16 f2bf(float f) {
  unsigned int u = __float_as_uint(f);
  u += 0x7FFFu + ((u >> 16) & 1u);
  return (u16)(u >> 16);
}

__device__ __forceinline__ float l0gate(float loga) {
  float s = 1.0f / (1.0f + expf(-loga));
  float v = s * 1.2f - 0.1f;   // sigmoid*(zeta-gamma)+gamma
  return fminf(fmaxf(v, 0.0f), 1.0f);
}

__device__ __forceinline__ void llds16(u16* lds, const u16* g) {
  __builtin_amdgcn_global_load_lds(
      (const __attribute__((address_space(1))) unsigned int*)g,
      (__attribute__((address_space(3))) unsigned int*)lds, 16, 0, 0);
}

// ---- ln_prep: blocks [0,M) do LayerNorm+bf16-cast of one row;
//      blocks [M, M+4096) fold the L0 gates into bf16 weight copies. ----
__global__ __launch_bounds__(256) void ln_prep(
    const float* __restrict__ x, const float* __restrict__ g,
    const float* __restrict__ b, u16* __restrict__ h1, int M,
    const float* __restrict__ dw, const float* __restrict__ uw,
    const float* __restrict__ dloga, const float* __restrict__ uloga,
    const int* __restrict__ lang,
    u16* __restrict__ dwb, u16* __restrict__ uwb) {
  const int tid = threadIdx.x;
  if ((int)blockIdx.x >= M) {
    const int lid = lang[0];
    const unsigned i = (blockIdx.x - M) * 256u + tid;
    dwb[i] = f2bf(dw[i] * l0gate(dloga[lid * 2048 + (i & 2047u)]));
    uwb[i] = f2bf(uw[i] * l0gate(uloga[lid * 512 + (i & 511u)]));
    return;
  }
  const int row = blockIdx.x;
  const float4* xr = (const float4*)(x + (size_t)row * 2048);
  float4 v0 = xr[tid * 2 + 0];
  float4 v1 = xr[tid * 2 + 1];
  float s = v0.x + v0.y + v0.z + v0.w + v1.x + v1.y + v1.z + v1.w;
  float q = v0.x * v0.x + v0.y * v0.y + v0.z * v0.z + v0.w * v0.w +
            v1.x * v1.x + v1.y * v1.y + v1.z * v1.z + v1.w * v1.w;
#pragma unroll
  for (int off = 32; off > 0; off >>= 1) {
    s += __shfl_down(s, off, 64);
    q += __shfl_down(q, off, 64);
  }
  __shared__ float ss[4], sq[4], sstat[2];
  const int wave = tid >> 6, lane = tid & 63;
  if (lane == 0) { ss[wave] = s; sq[wave] = q; }
  __syncthreads();
  if (tid == 0) {
    float S = ss[0] + ss[1] + ss[2] + ss[3];
    float Q = sq[0] + sq[1] + sq[2] + sq[3];
    float mu = S * (1.0f / 2048.0f);
    float var = Q * (1.0f / 2048.0f) - mu * mu;
    sstat[0] = mu;
    sstat[1] = rsqrtf(var + LN_EPS);
  }
  __syncthreads();
  const float mu = sstat[0], rs = sstat[1];
  const float4* g4 = (const float4*)g;
  const float4* b4 = (const float4*)b;
  float4 ga = g4[tid * 2], gb = g4[tid * 2 + 1];
  float4 ba = b4[tid * 2], bb = b4[tid * 2 + 1];
  union { u16 us[8]; uint4 u; } p;
  p.us[0] = f2bf((v0.x - mu) * rs * ga.x + ba.x);
  p.us[1] = f2bf((v0.y - mu) * rs * ga.y + ba.y);
  p.us[2] = f2bf((v0.z - mu) * rs * ga.z + ba.z);
  p.us[3] = f2bf((v0.w - mu) * rs * ga.w + ba.w);
  p.us[4] = f2bf((v1.x - mu) * rs * gb.x + bb.x);
  p.us[5] = f2bf((v1.y - mu) * rs * gb.y + bb.y);
  p.us[6] = f2bf((v1.z - mu) * rs * gb.z + bb.z);
  p.us[7] = f2bf((v1.w - mu) * rs * gb.w + bb.w);
  ((uint4*)(h1 + (size_t)row * 2048))[tid] = p.u;
}

// ---- gemm1: h2 = relu(h1 * dwb^T + down_b), bf16 out (R17-proven, unchanged) ----
__global__ __launch_bounds__(256) void gemm1(
    const u16* __restrict__ A, const u16* __restrict__ Bw,
    int M, int K, int NX,
    const float* __restrict__ bias,
    u16* __restrict__ outp) {
  const int N = 512;
  __shared__ __align__(16) char smem[81920];
  u16* Sg = (u16*)smem;                 // A buf i @ i*8192 (u16); B buf j @ 24576+j*8192
  float* Cs = (float*)smem;             // epilogue alias [128][128] f32 (64 KB)

  const int tid = threadIdx.x;
  const int wave = tid >> 6, lane = tid & 63;
  const int wr = (wave >> 1) * 64, wc = (wave & 1) * 64;
  const int lrow = lane & 15, lk = lane >> 4;

  const int nwg = gridDim.x;
  const int wg = (blockIdx.x & 7) * (nwg >> 3) + (blockIdx.x >> 3);
  const int bx = wg % NX, by = wg / NX;
  const size_t m0 = (size_t)by * 128, n0 = (size_t)bx * 128;

  f32x4 acc[4][4] = {};

  const int srow = lane >> 3;
  const int sslot = ((lane & 7) ^ ((lane >> 3) & 7)) * 8;
  auto SA = [&](int buf, int k0) {
#pragma unroll
    for (int c = 0; c < 4; ++c) {
      const int seg = c * 4 + wave;
      llds16(Sg + buf * 8192 + seg * 512,
             A + (m0 + seg * 8 + srow) * (size_t)K + (k0 + sslot));
    }
  };
  auto SB = [&](int buf, int k0) {
#pragma unroll
    for (int c = 0; c < 4; ++c) {
      const int seg = c * 4 + wave;
      llds16(Sg + 24576 + buf * 8192 + seg * 512,
             Bw + (n0 + seg * 8 + srow) * (size_t)K + (k0 + sslot));
    }
  };

  const int NT = K >> 6;   // 32
  SB(0, 0); SA(0, 0); SA(1, 64);

  for (int t = 0; t < NT; ++t) {
    if (t + 1 < NT) SB((t + 1) & 1, (t + 1) << 6);
    if (t + 2 < NT) SA((t + 2) % 3, (t + 2) << 6);
    if (t < NT - 2)       WAITV(12);
    else if (t == NT - 2) WAITV(8);
    else                  WAITV(0);
    BAR();

    const u16* Ab = Sg + (t % 3) * 8192;
    const u16* Bb = Sg + 24576 + (t & 1) * 8192;
#pragma unroll
    for (int ks = 0; ks < 2; ++ks) {
      bf16x8 af[4], bfr[4];
#pragma unroll
      for (int m = 0; m < 4; ++m)
        af[m] = *(const bf16x8*)&Ab[(wr + m * 16 + lrow) * 64 +
                                    ((unsigned)((ks * 4 + lk) ^ (lane & 7))) * 8];
#pragma unroll
      for (int n = 0; n < 4; ++n)
        bfr[n] = *(const bf16x8*)&Bb[(wc + n * 16 + lrow) * 64 +
                                     ((unsigned)((ks * 4 + lk) ^ (lane & 7))) * 8];
      __builtin_amdgcn_s_setprio(1);
#pragma unroll
      for (int m = 0; m < 4; ++m)
#pragma unroll
        for (int n = 0; n < 4; ++n)
          acc[m][n] = __builtin_amdgcn_mfma_f32_16x16x32_bf16(af[m], bfr[n],
                                                              acc[m][n], 0, 0, 0);
      __builtin_amdgcn_s_setprio(0);
    }
    LGKM0;
    BAR();
  }

#pragma unroll
  for (int n = 0; n < 4; ++n) {
    const int c = wc + n * 16 + lrow;
    const float bv = bias[n0 + c];
#pragma unroll
    for (int m = 0; m < 4; ++m) {
#pragma unroll
      for (int r = 0; r < 4; ++r) {
        const int row = wr + m * 16 + lk * 4 + r;
        Cs[row * 128 + ((c + ((row >> 2) << 3)) & 127)] = acc[m][n][r] + bv;
      }
    }
  }
  LGKM0;
  BAR();

#pragma unroll
  for (int j = 0; j < 8; ++j) {
    const int flat = tid * 8 + j * 2048;
    const int row = flat >> 7, c = flat & 127;
    const int cp = (c + ((row >> 2) << 3)) & 127;
    const f32x4 c0 = *(const f32x4*)&Cs[row * 128 + cp];
    const f32x4 c1 = *(const f32x4*)&Cs[row * 128 + cp + 4];
    union { u16 us[8]; uint4 u; } p;
    p.us[0] = f2bf(fmaxf(c0[0], 0.0f)); p.us[1] = f2bf(fmaxf(c0[1], 0.0f));
    p.us[2] = f2bf(fmaxf(c0[2], 0.0f)); p.us[3] = f2bf(fmaxf(c0[3], 0.0f));
    p.us[4] = f2bf(fmaxf(c1[0], 0.0f)); p.us[5] = f2bf(fmaxf(c1[1], 0.0f));
    p.us[6] = f2bf(fmaxf(c1[2], 0.0f)); p.us[7] = f2bf(fmaxf(c1[3], 0.0f));
    *(uint4*)&outp[(m0 + row) * (size_t)N + n0 + c] = p.u;
  }
}

// ---- gemm2: out = h2*uwb^T + up_b + resid; 128x64 tile, BK=64 (NT=8),
// double-buffered, paced f32x4 resid 1/iter. LDS 48KB staging + 32KB Cs alias
// = 49152 -> 3 blocks/CU (was 2). 4 waves, wave-tile 64x32, acc[4][2].
// Per-wave ledger (SB=2, SA=4, R=1): waits t0=7, t1..6=8, t7=2.
__global__ __launch_bounds__(256) void gemm2(
    const u16* __restrict__ A, const u16* __restrict__ Bw,
    int M, const float* __restrict__ bias,
    const float* __restrict__ resid, float* __restrict__ outp) {
  const int K = 512, N = 2048;
  __shared__ __align__(16) char smem[49152];
  u16* Sg = (u16*)smem;                 // A buf i @ i*8192 u16; B buf j @ 16384 + j*4096 u16
  float* Cs = (float*)smem;             // [128][64] f32 alias (32 KB)

  const int tid = threadIdx.x;
  const int wave = tid >> 6, lane = tid & 63;
  const int wr = (wave >> 1) * 64;      // wave rows: 0 or 64
  const int wcc = (wave & 1) * 32;      // wave cols: 0 or 32
  const int lrow = lane & 15, lk = lane >> 4;

  const int nwg = gridDim.x;            // 4096, %8==0
  const int wg = (blockIdx.x & 7) * (nwg >> 3) + (blockIdx.x >> 3);
  const int bx = wg & 31, by = wg >> 5; // NX=32
  const size_t m0 = (size_t)by * 128, n0 = (size_t)bx * 64;

  f32x4 acc[4][2] = {};

  const int srow = lane >> 3;
  const int sslot = ((lane & 7) ^ ((lane >> 3) & 7)) * 8;
  auto SA = [&](int buf, int k0) {
#pragma unroll
    for (int c = 0; c < 4; ++c) {
      const int seg = c * 4 + wave;     // 16 segs x 8 rows = 128 rows
      llds16(Sg + buf * 8192 + seg * 512,
             A + (m0 + seg * 8 + srow) * (size_t)K + (k0 + sslot));
    }
  };
  auto SB = [&](int buf, int k0) {
#pragma unroll
    for (int c = 0; c < 2; ++c) {
      const int seg = c * 4 + wave;     // 8 segs x 8 rows = 64 rows
      llds16(Sg + 16384 + buf * 4096 + seg * 512,
             Bw + (n0 + seg * 8 + srow) * (size_t)K + (k0 + sslot));
    }
  };

  f32x4 rsd[8];
  auto RSD = [&](int j) {
    const int flat = tid * 4 + j * 1024;
    const int row = flat >> 6, c = flat & 63;
    rsd[j] = *(const f32x4*)&resid[(m0 + row) * (size_t)N + n0 + c];
  };

  SB(0, 0); SA(0, 0);                    // 6 outstanding per wave

#pragma unroll
  for (int t = 0; t < 8; ++t) {
    if (t + 1 < 8) { SB((t + 1) & 1, (t + 1) * 64); SA((t + 1) & 1, (t + 1) * 64); }
    RSD(t);
    if (t == 0)      WAITV(7);           // after SA0: SB1 SA1 R0
    else if (t < 7)  WAITV(8);           // after SA_t: R_{t-1} SB_{t+1} SA_{t+1} R_t
    else             WAITV(2);           // after SA7: R6 R7
    BAR();

    const u16* Ab = Sg + (t & 1) * 8192;
    const u16* Bb = Sg + 16384 + (t & 1) * 4096;
#pragma unroll
    for (int ks = 0; ks < 2; ++ks) {
      bf16x8 af[4], bfr[2];
#pragma unroll
      for (int m = 0; m < 4; ++m)
        af[m] = *(const bf16x8*)&Ab[(wr + m * 16 + lrow) * 64 +
                                    ((unsigned)((ks * 4 + lk) ^ (lane & 7))) * 8];
#pragma unroll
      for (int n = 0; n < 2; ++n)
        bfr[n] = *(const bf16x8*)&Bb[(wcc + n * 16 + lrow) * 64 +
                                     ((unsigned)((ks * 4 + lk) ^ (lane & 7))) * 8];
      __builtin_amdgcn_s_setprio(1);
#pragma unroll
      for (int m = 0; m < 4; ++m)
#pragma unroll
        for (int n = 0; n < 2; ++n)
          acc[m][n] = __builtin_amdgcn_mfma_f32_16x16x32_bf16(af[m], bfr[n],
                                                              acc[m][n], 0, 0, 0);
      __builtin_amdgcn_s_setprio(0);
    }
    LGKM0;
    BAR();
  }

  // epilogue: bias into Cs (rotated: col' = (c + 8*(row>>2)) & 63), then
  // transpose-read + resid add + coalesced f32x4 store.
#pragma unroll
  for (int n = 0; n < 2; ++n) {
    const int c = wcc + n * 16 + lrow;
    const float bv = bias[n0 + c];
#pragma unroll
    for (int m = 0; m < 4; ++m) {
#pragma unroll
      for (int r = 0; r < 4; ++r) {
        const int row = wr + m * 16 + lk * 4 + r;
        Cs[row * 64 + ((c + ((row >> 2) << 3)) & 63)] = acc[m][n][r] + bv;
      }
    }
  }
  LGKM0;
  BAR();

#pragma unroll
  for (int j = 0; j < 8; ++j) {
    const int flat = tid * 4 + j * 1024;
    const int row = flat >> 6, c = flat & 63;
    const f32x4 cc = *(const f32x4*)&Cs[row * 64 + ((c + ((row >> 2) << 3)) & 63)];
    f32x4 o;
    o[0] = cc[0] + rsd[j][0]; o[1] = cc[1] + rsd[j][1];
    o[2] = cc[2] + rsd[j][2]; o[3] = cc[3] + rsd[j][3];
    *(f32x4*)&outp[(m0 + row) * (size_t)N + n0 + c] = o;
  }
}

extern "C" void kernel_launch(void* const* d_in, const int* in_sizes, int n_in,
                              void* d_out, int out_size, void* d_ws, size_t ws_size,
                              hipStream_t stream) {
  const float* x         = (const float*)d_in[0];
  const float* down_w    = (const float*)d_in[1];
  const float* down_b    = (const float*)d_in[2];
  const float* up_w      = (const float*)d_in[3];
  const float* up_b      = (const float*)d_in[4];
  const float* ln_g      = (const float*)d_in[5];
  const float* ln_b      = (const float*)d_in[6];
  const float* down_loga = (const float*)d_in[7];
  const float* up_loga   = (const float*)d_in[8];
  const int*   lang      = (const int*)d_in[9];

  const int D = 2048, BNK = 512;
  const int M = in_sizes[0] / D;  // 16384

  char* ws = (char*)d_ws;
  u16* h1  = (u16*)ws;                                   // [M][D] bf16
  u16* h2  = (u16*)(ws + (size_t)M * D * 2);             // [M][BNK] bf16
  u16* dwb = (u16*)(ws + (size_t)M * D * 2 + (size_t)M * BNK * 2);  // [BNK][D]
  u16* uwb = dwb + (size_t)BNK * D;                      // [D][BNK]

  // fused: LN rows (blocks 0..M-1) + weight prep (blocks M..M+4095)
  ln_prep<<<M + (BNK * D) / 256, 256, 0, stream>>>(
      x, ln_g, ln_b, h1, M, down_w, up_w, down_loga, up_loga, lang, dwb, uwb);
  gemm1<<<(M / 128) * (BNK / 128), 256, 0, stream>>>(h1, dwb, M, D, BNK / 128,
                                                     down_b, h2);
  gemm2<<<(M / 128) * (D / 64), 256, 0, stream>>>(h2, uwb, M, up_b, x,
                                                  (float*)d_out);
}

// Round 19
// 145.763 us; speedup vs baseline: 1.0777x; 1.0777x over previous
//
#include <hip/hip_runtime.h>
#include <cstdint>
#include <cstddef>

typedef unsigned short u16;
typedef __attribute__((ext_vector_type(4))) float f32x4;
typedef __attribute__((ext_vector_type(8))) short bf16x8;

#define LN_EPS 1e-5f
#define WAITV(n) asm volatile("s_waitcnt vmcnt(" #n ")" ::: "memory")
#define LGKM0    asm volatile("s_waitcnt lgkmcnt(0)" ::: "memory")
#define BAR()    do { __builtin_amdgcn_s_barrier(); asm volatile("" ::: "memory"); } while (0)

__device__ __forceinline__ u16 f2bf(float f) {
  unsigned int u = __float_as_uint(f);
  u += 0x7FFFu + ((u >> 16) & 1u);
  return (u16)(u >> 16);
}

__device__ __forceinline__ float l0gate(float loga) {
  float s = 1.0f / (1.0f + expf(-loga));
  float v = s * 1.2f - 0.1f;   // sigmoid*(zeta-gamma)+gamma
  return fminf(fmaxf(v, 0.0f), 1.0f);
}

__device__ __forceinline__ void llds16(u16* lds, const u16* g) {
  __builtin_amdgcn_global_load_lds(
      (const __attribute__((address_space(1))) unsigned int*)g,
      (__attribute__((address_space(3))) unsigned int*)lds, 16, 0, 0);
}

// ---- ln_prep: blocks [0,M) do LayerNorm+bf16-cast of one row;
//      blocks [M, M+4096) fold the L0 gates into bf16 weight copies. ----
__global__ __launch_bounds__(256) void ln_prep(
    const float* __restrict__ x, const float* __restrict__ g,
    const float* __restrict__ b, u16* __restrict__ h1, int M,
    const float* __restrict__ dw, const float* __restrict__ uw,
    const float* __restrict__ dloga, const float* __restrict__ uloga,
    const int* __restrict__ lang,
    u16* __restrict__ dwb, u16* __restrict__ uwb) {
  const int tid = threadIdx.x;
  if ((int)blockIdx.x >= M) {
    const int lid = lang[0];
    const unsigned i = (blockIdx.x - M) * 256u + tid;
    dwb[i] = f2bf(dw[i] * l0gate(dloga[lid * 2048 + (i & 2047u)]));
    uwb[i] = f2bf(uw[i] * l0gate(uloga[lid * 512 + (i & 511u)]));
    return;
  }
  const int row = blockIdx.x;
  const float4* xr = (const float4*)(x + (size_t)row * 2048);
  float4 v0 = xr[tid * 2 + 0];
  float4 v1 = xr[tid * 2 + 1];
  float s = v0.x + v0.y + v0.z + v0.w + v1.x + v1.y + v1.z + v1.w;
  float q = v0.x * v0.x + v0.y * v0.y + v0.z * v0.z + v0.w * v0.w +
            v1.x * v1.x + v1.y * v1.y + v1.z * v1.z + v1.w * v1.w;
#pragma unroll
  for (int off = 32; off > 0; off >>= 1) {
    s += __shfl_down(s, off, 64);
    q += __shfl_down(q, off, 64);
  }
  __shared__ float ss[4], sq[4], sstat[2];
  const int wave = tid >> 6, lane = tid & 63;
  if (lane == 0) { ss[wave] = s; sq[wave] = q; }
  __syncthreads();
  if (tid == 0) {
    float S = ss[0] + ss[1] + ss[2] + ss[3];
    float Q = sq[0] + sq[1] + sq[2] + sq[3];
    float mu = S * (1.0f / 2048.0f);
    float var = Q * (1.0f / 2048.0f) - mu * mu;
    sstat[0] = mu;
    sstat[1] = rsqrtf(var + LN_EPS);
  }
  __syncthreads();
  const float mu = sstat[0], rs = sstat[1];
  const float4* g4 = (const float4*)g;
  const float4* b4 = (const float4*)b;
  float4 ga = g4[tid * 2], gb = g4[tid * 2 + 1];
  float4 ba = b4[tid * 2], bb = b4[tid * 2 + 1];
  union { u16 us[8]; uint4 u; } p;
  p.us[0] = f2bf((v0.x - mu) * rs * ga.x + ba.x);
  p.us[1] = f2bf((v0.y - mu) * rs * ga.y + ba.y);
  p.us[2] = f2bf((v0.z - mu) * rs * ga.z + ba.z);
  p.us[3] = f2bf((v0.w - mu) * rs * ga.w + ba.w);
  p.us[4] = f2bf((v1.x - mu) * rs * gb.x + bb.x);
  p.us[5] = f2bf((v1.y - mu) * rs * gb.y + bb.y);
  p.us[6] = f2bf((v1.z - mu) * rs * gb.z + bb.z);
  p.us[7] = f2bf((v1.w - mu) * rs * gb.w + bb.w);
  ((uint4*)(h1 + (size_t)row * 2048))[tid] = p.u;
}

// ---- gemm1: h2 = relu(h1 * dwb^T + down_b), bf16 out ----
// 128x128 tile, BK=64. A (h1) TRIPLE-buffered (depth-2 prefetch);
// B (weights, L2-resident) double-buffered. LDS 80 KB -> 2 blocks/CU.
__global__ __launch_bounds__(256) void gemm1(
    const u16* __restrict__ A, const u16* __restrict__ Bw,
    int M, int K, int NX,
    const float* __restrict__ bias,
    u16* __restrict__ outp) {
  const int N = 512;
  __shared__ __align__(16) char smem[81920];
  u16* Sg = (u16*)smem;                 // A buf i @ i*8192 (u16); B buf j @ 24576+j*8192
  float* Cs = (float*)smem;             // epilogue alias [128][128] f32 (64 KB)

  const int tid = threadIdx.x;
  const int wave = tid >> 6, lane = tid & 63;
  const int wr = (wave >> 1) * 64, wc = (wave & 1) * 64;
  const int lrow = lane & 15, lk = lane >> 4;

  const int nwg = gridDim.x;
  const int wg = (blockIdx.x & 7) * (nwg >> 3) + (blockIdx.x >> 3);
  const int bx = wg % NX, by = wg / NX;
  const size_t m0 = (size_t)by * 128, n0 = (size_t)bx * 128;

  f32x4 acc[4][4] = {};

  const int srow = lane >> 3;
  const int sslot = ((lane & 7) ^ ((lane >> 3) & 7)) * 8;
  auto SA = [&](int buf, int k0) {
#pragma unroll
    for (int c = 0; c < 4; ++c) {
      const int seg = c * 4 + wave;
      llds16(Sg + buf * 8192 + seg * 512,
             A + (m0 + seg * 8 + srow) * (size_t)K + (k0 + sslot));
    }
  };
  auto SB = [&](int buf, int k0) {
#pragma unroll
    for (int c = 0; c < 4; ++c) {
      const int seg = c * 4 + wave;
      llds16(Sg + 24576 + buf * 8192 + seg * 512,
             Bw + (n0 + seg * 8 + srow) * (size_t)K + (k0 + sslot));
    }
  };

  const int NT = K >> 6;   // 32
  SB(0, 0); SA(0, 0); SA(1, 64);

  for (int t = 0; t < NT; ++t) {
    if (t + 1 < NT) SB((t + 1) & 1, (t + 1) << 6);
    if (t + 2 < NT) SA((t + 2) % 3, (t + 2) << 6);
    if (t < NT - 2)       WAITV(12);
    else if (t == NT - 2) WAITV(8);
    else                  WAITV(0);
    BAR();

    const u16* Ab = Sg + (t % 3) * 8192;
    const u16* Bb = Sg + 24576 + (t & 1) * 8192;
#pragma unroll
    for (int ks = 0; ks < 2; ++ks) {
      bf16x8 af[4], bfr[4];
#pragma unroll
      for (int m = 0; m < 4; ++m)
        af[m] = *(const bf16x8*)&Ab[(wr + m * 16 + lrow) * 64 +
                                    ((unsigned)((ks * 4 + lk) ^ (lane & 7))) * 8];
#pragma unroll
      for (int n = 0; n < 4; ++n)
        bfr[n] = *(const bf16x8*)&Bb[(wc + n * 16 + lrow) * 64 +
                                     ((unsigned)((ks * 4 + lk) ^ (lane & 7))) * 8];
      __builtin_amdgcn_s_setprio(1);
#pragma unroll
      for (int m = 0; m < 4; ++m)
#pragma unroll
        for (int n = 0; n < 4; ++n)
          acc[m][n] = __builtin_amdgcn_mfma_f32_16x16x32_bf16(af[m], bfr[n],
                                                              acc[m][n], 0, 0, 0);
      __builtin_amdgcn_s_setprio(0);
    }
    LGKM0;
    BAR();
  }

  // epilogue: +bias, relu, LDS-transpose (rotated), coalesced bf16 store
#pragma unroll
  for (int n = 0; n < 4; ++n) {
    const int c = wc + n * 16 + lrow;
    const float bv = bias[n0 + c];
#pragma unroll
    for (int m = 0; m < 4; ++m) {
#pragma unroll
      for (int r = 0; r < 4; ++r) {
        const int row = wr + m * 16 + lk * 4 + r;
        Cs[row * 128 + ((c + ((row >> 2) << 3)) & 127)] = acc[m][n][r] + bv;
      }
    }
  }
  LGKM0;
  BAR();

#pragma unroll
  for (int j = 0; j < 8; ++j) {
    const int flat = tid * 8 + j * 2048;
    const int row = flat >> 7, c = flat & 127;
    const int cp = (c + ((row >> 2) << 3)) & 127;
    const f32x4 c0 = *(const f32x4*)&Cs[row * 128 + cp];
    const f32x4 c1 = *(const f32x4*)&Cs[row * 128 + cp + 4];
    union { u16 us[8]; uint4 u; } p;
    p.us[0] = f2bf(fmaxf(c0[0], 0.0f)); p.us[1] = f2bf(fmaxf(c0[1], 0.0f));
    p.us[2] = f2bf(fmaxf(c0[2], 0.0f)); p.us[3] = f2bf(fmaxf(c0[3], 0.0f));
    p.us[4] = f2bf(fmaxf(c1[0], 0.0f)); p.us[5] = f2bf(fmaxf(c1[1], 0.0f));
    p.us[6] = f2bf(fmaxf(c1[2], 0.0f)); p.us[7] = f2bf(fmaxf(c1[3], 0.0f));
    *(uint4*)&outp[(m0 + row) * (size_t)N + n0 + c] = p.u;
  }
}

// ---- gemm2: out = h2*uwb^T + up_b + resid; K=512, unrolled.
// A (h2) triple-buffered depth-2; B double-buffered; resid x-loads paced
// 2/iter into the counted schedule. (R15/R17-proven best.)
__global__ __launch_bounds__(256) void gemm2(
    const u16* __restrict__ A, const u16* __restrict__ Bw,
    int M, const float* __restrict__ bias,
    const float* __restrict__ resid, float* __restrict__ outp) {
  const int K = 512, N = 2048;
  __shared__ __align__(16) char smem[81920];
  u16* Sg = (u16*)smem;                 // A buf i @ i*8192; B buf j @ 24576 + j*8192
  float* Cs = (float*)smem;

  const int tid = threadIdx.x;
  const int wave = tid >> 6, lane = tid & 63;
  const int wr = (wave >> 1) * 64, wc = (wave & 1) * 64;
  const int lrow = lane & 15, lk = lane >> 4;

  const int nwg = gridDim.x;            // 2048, %8==0
  const int wg = (blockIdx.x & 7) * (nwg >> 3) + (blockIdx.x >> 3);
  const int bx = wg & 15, by = wg >> 4; // NX=16
  const size_t m0 = (size_t)by * 128, n0 = (size_t)bx * 128;

  f32x4 acc[4][4] = {};

  const int srow = lane >> 3;
  const int sslot = ((lane & 7) ^ ((lane >> 3) & 7)) * 8;
  auto SA = [&](int buf, int k0) {
#pragma unroll
    for (int c = 0; c < 4; ++c) {
      const int seg = c * 4 + wave;
      llds16(Sg + buf * 8192 + seg * 512,
             A + (m0 + seg * 8 + srow) * (size_t)K + (k0 + sslot));
    }
  };
  auto SB = [&](int buf, int k0) {
#pragma unroll
    for (int c = 0; c < 4; ++c) {
      const int seg = c * 4 + wave;
      llds16(Sg + 24576 + buf * 8192 + seg * 512,
             Bw + (n0 + seg * 8 + srow) * (size_t)K + (k0 + sslot));
    }
  };

  f32x4 rsd[16];
  auto RSD = [&](int j) {
    const int flat = tid * 4 + j * 1024;
    const int row = flat >> 7, c = flat & 127;
    rsd[j] = *(const f32x4*)&resid[(m0 + row) * (size_t)N + n0 + c];
  };

  SB(0, 0); SA(0, 0); SA(1, 64);

#pragma unroll
  for (int t = 0; t < 8; ++t) {
    if (t + 1 < 8) SB((t + 1) & 1, (t + 1) * 64);
    if (t + 2 < 8) SA((t + 2) % 3, (t + 2) * 64);
    if (t < 7) { RSD(2 * t); RSD(2 * t + 1); }
    else       { RSD(14); RSD(15); }
    if (t == 0)      WAITV(14);
    else if (t <= 5) WAITV(16);
    else if (t == 6) WAITV(12);
    else             WAITV(4);   // only register resid loads left in flight
    BAR();

    const u16* Ab = Sg + (t % 3) * 8192;
    const u16* Bb = Sg + 24576 + (t & 1) * 8192;
#pragma unroll
    for (int ks = 0; ks < 2; ++ks) {
      bf16x8 af[4], bfr[4];
#pragma unroll
      for (int m = 0; m < 4; ++m)
        af[m] = *(const bf16x8*)&Ab[(wr + m * 16 + lrow) * 64 +
                                    ((unsigned)((ks * 4 + lk) ^ (lane & 7))) * 8];
#pragma unroll
      for (int n = 0; n < 4; ++n)
        bfr[n] = *(const bf16x8*)&Bb[(wc + n * 16 + lrow) * 64 +
                                     ((unsigned)((ks * 4 + lk) ^ (lane & 7))) * 8];
      __builtin_amdgcn_s_setprio(1);
#pragma unroll
      for (int m = 0; m < 4; ++m)
#pragma unroll
        for (int n = 0; n < 4; ++n)
          acc[m][n] = __builtin_amdgcn_mfma_f32_16x16x32_bf16(af[m], bfr[n],
                                                              acc[m][n], 0, 0, 0);
      __builtin_amdgcn_s_setprio(0);
    }
    LGKM0;
    BAR();
  }

  // epilogue: bias into Cs (rotated), transpose-read, add resid, f32 store
#pragma unroll
  for (int n = 0; n < 4; ++n) {
    const int c = wc + n * 16 + lrow;
    const float bv = bias[n0 + c];
#pragma unroll
    for (int m = 0; m < 4; ++m) {
#pragma unroll
      for (int r = 0; r < 4; ++r) {
        const int row = wr + m * 16 + lk * 4 + r;
        Cs[row * 128 + ((c + ((row >> 2) << 3)) & 127)] = acc[m][n][r] + bv;
      }
    }
  }
  LGKM0;
  BAR();

#pragma unroll
  for (int j = 0; j < 16; ++j) {
    const int flat = tid * 4 + j * 1024;
    const int row = flat >> 7, c = flat & 127;
    const f32x4 cc = *(const f32x4*)&Cs[row * 128 + ((c + ((row >> 2) << 3)) & 127)];
    f32x4 o;
    o[0] = cc[0] + rsd[j][0]; o[1] = cc[1] + rsd[j][1];
    o[2] = cc[2] + rsd[j][2]; o[3] = cc[3] + rsd[j][3];
    *(f32x4*)&outp[(m0 + row) * (size_t)N + n0 + c] = o;
  }
}

extern "C" void kernel_launch(void* const* d_in, const int* in_sizes, int n_in,
                              void* d_out, int out_size, void* d_ws, size_t ws_size,
                              hipStream_t stream) {
  const float* x         = (const float*)d_in[0];
  const float* down_w    = (const float*)d_in[1];
  const float* down_b    = (const float*)d_in[2];
  const float* up_w      = (const float*)d_in[3];
  const float* up_b      = (const float*)d_in[4];
  const float* ln_g      = (const float*)d_in[5];
  const float* ln_b      = (const float*)d_in[6];
  const float* down_loga = (const float*)d_in[7];
  const float* up_loga   = (const float*)d_in[8];
  const int*   lang      = (const int*)d_in[9];

  const int D = 2048, BNK = 512;
  const int M = in_sizes[0] / D;  // 16384

  char* ws = (char*)d_ws;
  u16* h1  = (u16*)ws;                                   // [M][D] bf16
  u16* h2  = (u16*)(ws + (size_t)M * D * 2);             // [M][BNK] bf16
  u16* dwb = (u16*)(ws + (size_t)M * D * 2 + (size_t)M * BNK * 2);  // [BNK][D]
  u16* uwb = dwb + (size_t)BNK * D;                      // [D][BNK]

  // fused: LN rows (blocks 0..M-1) + weight prep (blocks M..M+4095)
  ln_prep<<<M + (BNK * D) / 256, 256, 0, stream>>>(
      x, ln_g, ln_b, h1, M, down_w, up_w, down_loga, up_loga, lang, dwb, uwb);
  gemm1<<<(M / 128) * (BNK / 128), 256, 0, stream>>>(h1, dwb, M, D, BNK / 128,
                                                     down_b, h2);
  gemm2<<<(M / 128) * (D / 128), 256, 0, stream>>>(h2, uwb, M, up_b, x,
                                                   (float*)d_out);
}